// Round 4
// baseline (1575.369 us; speedup 1.0000x reference)
//
#include <hip/hip_runtime.h>
#include <math.h>

// RNNLayer: out[t] = tanh(x[t] @ Wx + b + h_{t-1} @ Wh), h_{-1} = h0
// S=128, B=128, D=1024. Inputs/outputs fp32.
//
// Round 9: ONE fused kernel, 384 blocks x 512 threads, 2 blocks/CU
// (__launch_bounds__(512,4): 4 waves/EU -> 16 waves/CU; LDS unioned to
// 70.3 KB so any 2 blocks fit 160 KB -> all 384 blocks co-resident).
//
// Blocks 0..255: xp role (persistent xp GEMM, INTERLEAVED steps).
//   Block (tg,bt,ct) computes xp[t] for t = 2*tt + tg -> xp production runs
//   at 2x the scan's consumption rate, so the scan is gated only at t=0/1.
//   Waves split by HI/LO ROLE over full K (not k-halves) to fit the 128-VGPR
//   cap: role-0 waves hold Bhi[32] (64 regs), compute xhi*Whi + xlo*Whi;
//   role-1 waves hold Blo[32], compute xhi*Wlo; redS pairwise reduction.
//   xp written to out[] via relaxed AGENT stores (IC write-through), drained
//   with s_waitcnt vmcnt(0), then a per-block flag is posted.
// Blocks 256..383: scan role (identical to round-8 scan), plus:
//   - spins the xp flag for (t&1, bt, ct) then bypass-loads its 4 xpv
//     (latency hidden under h-staging + MFMA);
//   - out[] nt-stores moved AFTER the scan flag post (drain now waits only
//     the single hX store; out stores complete under the flag spin);
//   - s_sleep(1) in spins.
// Cross-block h exchange (hX bf16 side-channel, parity double-buffered) and
// per-batch-group barriers are unchanged from round 8.
// Workspace: scanflags 8 KB @0, xpflags 16 KB @8192, hX 512 KB @24576.

#define DIM 1024
#define BATCH 128
#define SEQ 128
#define BD (BATCH * DIM)
#define XNB 256       // xp-role blocks
#define SNB 128       // scan-role blocks
#define TNB 384       // total blocks
#define GRP 16        // scan blocks per batch-group
#define HSTR 1032     // LDS row stride in ushorts (16B-aligned rows, bank spread)
#define FLAGSTR 16    // uints per flag slot (64 B)
#define HXGRP 16384   // ushorts per hX group slab (16 rows x 1024 cols)

typedef __attribute__((ext_vector_type(8))) short bf16x8;
typedef __attribute__((ext_vector_type(4))) float f32x4;

static __device__ __forceinline__ unsigned short f2bf_rne(float f) {
    unsigned u = __builtin_bit_cast(unsigned, f);
    unsigned r = (u + 0x7FFFu + ((u >> 16) & 1u)) >> 16;
    return (unsigned short)r;
}
static __device__ __forceinline__ float bf2f(unsigned short h) {
    return __builtin_bit_cast(float, ((unsigned)h) << 16);
}

__global__ __launch_bounds__(512, 4) void rnn_fused(
    const float* __restrict__ x,
    const float* __restrict__ h0,
    const float* __restrict__ Wx,
    const float* __restrict__ Wh,
    const float* __restrict__ bias,
    float* out,
    unsigned* scanflags,
    unsigned* xpflags,
    unsigned short* hX)
{
    // Unioned LDS: xp uses smA=x_hi, smB=x_lo; scan uses smA=h tile.
    __shared__ unsigned short smA[16 * HSTR];   // 33 KB
    __shared__ unsigned short smB[16 * HSTR];   // 33 KB
    __shared__ f32x4 redS[256];                 // 4 KB

    const int tid = threadIdx.x;
    const int gid = blockIdx.x;
    const int w = tid >> 6;          // wave 0..7
    const int l = tid & 63;
    const int n = l & 15;
    const int q = l >> 4;

    const int sr = tid >> 5;         // staging: row 0..15 (32 threads/row)
    const int su = tid & 31;         // staging: ulong lane within row

    if (gid < XNB) {
        // ================= xp role =================
        const int tg = gid >> 7;         // t parity
        const int bt = (gid >> 4) & 7;
        const int ct = gid & 15;
        const int B0 = bt * 16;
        const int Cb = ct * 64;
        const int cb = Cb + (w >> 1) * 16;
        const int role = w & 1;          // 0: Whi (x_hi + x_lo passes), 1: Wlo

        // resident Wx fragments for this role, full K (64 VGPRs)
        bf16x8 Bfr[32];
        #pragma unroll
        for (int s = 0; s < 32; ++s) {
            bf16x8 fr;
            #pragma unroll
            for (int j = 0; j < 8; ++j) {
                const int k = 32 * s + q * 8 + j;
                const float wv = Wx[(size_t)k * DIM + cb + n];
                const unsigned short h16 = f2bf_rne(wv);
                fr[j] = role ? (short)f2bf_rne(wv - bf2f(h16)) : (short)h16;
            }
            Bfr[s] = fr;
        }
        const float bv = bias[cb + n];

        for (int tt = 0; tt < SEQ / 2; ++tt) {
            const int t = 2 * tt + tg;
            const float* xT = x + (size_t)t * BD + (size_t)B0 * DIM;
            float* outT = out + (size_t)t * BD;

            // ---- stage x tile: fp32 -> bf16 hi(smA) + lo(smB) ----
            {
                const unsigned long long* srow =
                    (const unsigned long long*)(xT + (size_t)sr * DIM);
                unsigned short* dh = &smA[sr * HSTR];
                unsigned short* dl = &smB[sr * HSTR];
                #pragma unroll
                for (int i = 0; i < 16; ++i) {
                    const unsigned long long v = srow[su + 32 * i];
                    const float f0 = __builtin_bit_cast(float, (unsigned)(v & 0xFFFFFFFFull));
                    const float f1 = __builtin_bit_cast(float, (unsigned)(v >> 32));
                    const unsigned short h0v = f2bf_rne(f0);
                    const unsigned short h1v = f2bf_rne(f1);
                    const unsigned short l0v = f2bf_rne(f0 - bf2f(h0v));
                    const unsigned short l1v = f2bf_rne(f1 - bf2f(h1v));
                    *(unsigned*)(dh + 2 * (su + 32 * i)) =
                        (unsigned)h0v | ((unsigned)h1v << 16);
                    *(unsigned*)(dl + 2 * (su + 32 * i)) =
                        (unsigned)l0v | ((unsigned)l1v << 16);
                }
            }
            __syncthreads();

            // ---- MFMA, full K, role-split ----
            f32x4 acc = {0.f, 0.f, 0.f, 0.f};
            {
                const unsigned short* rh = &smA[(l & 15) * HSTR];
                const unsigned short* rl = &smB[(l & 15) * HSTR];
                if (!role) {
                    #pragma unroll
                    for (int s = 0; s < 32; ++s) {
                        const bf16x8 ah = *(const bf16x8*)(rh + 32 * s + 8 * q);
                        const bf16x8 al = *(const bf16x8*)(rl + 32 * s + 8 * q);
                        acc = __builtin_amdgcn_mfma_f32_16x16x32_bf16(ah, Bfr[s], acc, 0, 0, 0);
                        acc = __builtin_amdgcn_mfma_f32_16x16x32_bf16(al, Bfr[s], acc, 0, 0, 0);
                    }
                } else {
                    #pragma unroll
                    for (int s = 0; s < 32; ++s) {
                        const bf16x8 ah = *(const bf16x8*)(rh + 32 * s + 8 * q);
                        acc = __builtin_amdgcn_mfma_f32_16x16x32_bf16(ah, Bfr[s], acc, 0, 0, 0);
                    }
                }
            }

            if (role) redS[(w >> 1) * 64 + l] = acc;
            __syncthreads();

            if (!role) {
                const f32x4 p = redS[(w >> 1) * 64 + l];
                // C/D layout: col = lane&15, row = q*4 + reg
                #pragma unroll
                for (int i = 0; i < 4; ++i)
                    __hip_atomic_store(&outT[(size_t)(B0 + q * 4 + i) * DIM + cb + n],
                                       acc[i] + p[i] + bv,
                                       __ATOMIC_RELAXED, __HIP_MEMORY_SCOPE_AGENT);
            }

            // drain xp stores to IC, then post this step's flag
            asm volatile("s_waitcnt vmcnt(0)" ::: "memory");
            __syncthreads();
            if (tid == 0)
                __hip_atomic_store(&xpflags[gid * FLAGSTR], (unsigned)(tt + 1),
                                   __ATOMIC_RELAXED, __HIP_MEMORY_SCOPE_AGENT);
        }
    } else {
        // ================= scan role =================
        const int bid = gid - XNB;       // 0..127
        const int bt  = bid >> 4;
        const int ct  = bid & 15;
        const int B0  = bt * 16;
        const int Cb  = ct * 64;
        const int cb  = Cb + (w >> 1) * 16;
        const int K0  = (w & 1) * 512;

        // resident Wh fragments (bf16 hi + lo), k-half split (128 VGPRs)
        bf16x8 Bhi[16], Blo[16];
        #pragma unroll
        for (int s = 0; s < 16; ++s) {
            bf16x8 hi, lo;
            #pragma unroll
            for (int j = 0; j < 8; ++j) {
                const int k = K0 + 32 * s + q * 8 + j;
                const float wv = Wh[(size_t)k * DIM + cb + n];
                const unsigned short h16 = f2bf_rne(wv);
                hi[j] = (short)h16;
                lo[j] = (short)f2bf_rne(wv - bf2f(h16));
            }
            Bhi[s] = hi;
            Blo[s] = lo;
        }

        const int qq = tid & 3;            // t>0 staging: row quad
        const int c0 = (tid >> 2) & 127;   // t>0 staging: col-group base

        for (int t = 0; t < SEQ; ++t) {
            float* outT = out + (size_t)t * BD;

            // ---- xp: spin producer flag, then bypass-load 4 values ----
            float xpv[4];
            if (!(w & 1)) {
                const unsigned* xslot =
                    &xpflags[(((t & 1) << 7) + bt * 16 + ct) * FLAGSTR];
                const unsigned need = (unsigned)(t >> 1) + 1u;
                while (__hip_atomic_load(xslot, __ATOMIC_RELAXED,
                                         __HIP_MEMORY_SCOPE_AGENT) < need)
                    __builtin_amdgcn_s_sleep(1);
                #pragma unroll
                for (int i = 0; i < 4; ++i)
                    xpv[i] = __hip_atomic_load(
                        &outT[(size_t)(B0 + q * 4 + i) * DIM + cb + n],
                        __ATOMIC_RELAXED, __HIP_MEMORY_SCOPE_AGENT);
            }

            // ---- stage h tile into row-major LDS (smA) ----
            if (t == 0) {
                const float* hsrc = h0 + (size_t)B0 * DIM;
                const unsigned long long* srow =
                    (const unsigned long long*)(hsrc + (size_t)sr * DIM);
                unsigned short* drow = &smA[sr * HSTR];
                #pragma unroll
                for (int i = 0; i < 16; ++i) {
                    const unsigned long long v = srow[su + 32 * i];
                    const float f0 = __builtin_bit_cast(float, (unsigned)(v & 0xFFFFFFFFull));
                    const float f1 = __builtin_bit_cast(float, (unsigned)(v >> 32));
                    const unsigned pk =
                        (unsigned)f2bf_rne(f0) | ((unsigned)f2bf_rne(f1) << 16);
                    *(unsigned*)(drow + 2 * (su + 32 * i)) = pk;
                }
            } else {
                // bf16 side-channel: 8 x 8B bypass loads + 4x4 transpose
                const unsigned short* gX = hX + (size_t)((t - 1) & 1) * (8 * HXGRP)
                                              + (size_t)bt * HXGRP;
                #pragma unroll
                for (int half = 0; half < 2; ++half) {
                    const int cp = c0 + half * 128;
                    unsigned long long L[4];
                    #pragma unroll
                    for (int cc = 0; cc < 4; ++cc)
                        L[cc] = __hip_atomic_load(
                            (const unsigned long long*)(gX + (size_t)(4 * cp + cc) * 16 + qq * 4),
                            __ATOMIC_RELAXED, __HIP_MEMORY_SCOPE_AGENT);
                    #pragma unroll
                    for (int i = 0; i < 2; ++i) {
                        const unsigned a0 = (unsigned)(L[0] >> (32 * i));
                        const unsigned a1 = (unsigned)(L[1] >> (32 * i));
                        const unsigned a2 = (unsigned)(L[2] >> (32 * i));
                        const unsigned a3 = (unsigned)(L[3] >> (32 * i));
                        const unsigned r0w0 = (a0 & 0xFFFFu) | (a1 << 16);
                        const unsigned r0w1 = (a2 & 0xFFFFu) | (a3 << 16);
                        const unsigned r1w0 = (a0 >> 16) | (a1 & 0xFFFF0000u);
                        const unsigned r1w1 = (a2 >> 16) | (a3 & 0xFFFF0000u);
                        *(unsigned long long*)&smA[(4 * qq + 2 * i) * HSTR + 4 * cp] =
                            (unsigned long long)r0w0 | ((unsigned long long)r0w1 << 32);
                        *(unsigned long long*)&smA[(4 * qq + 2 * i + 1) * HSTR + 4 * cp] =
                            (unsigned long long)r1w0 | ((unsigned long long)r1w1 << 32);
                    }
                }
            }

            __syncthreads();

            // ---- MFMA over this wave's k-half ----
            f32x4 acc = {0.f, 0.f, 0.f, 0.f};
            {
                const unsigned short* hrow = &smA[(l & 15) * HSTR + K0];
                #pragma unroll
                for (int s = 0; s < 16; ++s) {
                    const bf16x8 a = *(const bf16x8*)(hrow + 32 * s + 8 * q);
                    acc = __builtin_amdgcn_mfma_f32_16x16x32_bf16(a, Bhi[s], acc, 0, 0, 0);
                    acc = __builtin_amdgcn_mfma_f32_16x16x32_bf16(a, Blo[s], acc, 0, 0, 0);
                }
            }

            if (w & 1) redS[(w >> 1) * 64 + l] = acc;
            __syncthreads();

            float v0, v1, v2, v3;
            if (!(w & 1)) {
                const f32x4 p = redS[(w >> 1) * 64 + l];
                v0 = tanhf(acc[0] + p[0] + xpv[0]);
                v1 = tanhf(acc[1] + p[1] + xpv[1]);
                v2 = tanhf(acc[2] + p[2] + xpv[2]);
                v3 = tanhf(acc[3] + p[3] + xpv[3]);
                // bf16 side-channel store (the only store gating the flag)
                const unsigned p0 = (unsigned)f2bf_rne(v0) | ((unsigned)f2bf_rne(v1) << 16);
                const unsigned p1 = (unsigned)f2bf_rne(v2) | ((unsigned)f2bf_rne(v3) << 16);
                unsigned short* gW = hX + (size_t)(t & 1) * (8 * HXGRP) + (size_t)bt * HXGRP;
                __hip_atomic_store(
                    (unsigned long long*)(gW + (size_t)(cb + n) * 16 + q * 4),
                    (unsigned long long)p0 | ((unsigned long long)p1 << 32),
                    __ATOMIC_RELAXED, __HIP_MEMORY_SCOPE_AGENT);
            }

            if (t < SEQ - 1) {
                // drain hX store to IC; post my flag
                asm volatile("s_waitcnt vmcnt(0)" ::: "memory");
                __syncthreads();
                if (tid == 0)
                    __hip_atomic_store(&scanflags[bid * FLAGSTR], (unsigned)(t + 1),
                                       __ATOMIC_RELAXED, __HIP_MEMORY_SCOPE_AGENT);
            }

            // fp32 output stores AFTER the flag: complete under the spin
            if (!(w & 1)) {
                __builtin_nontemporal_store(v0, &outT[(size_t)(B0 + q * 4 + 0) * DIM + cb + n]);
                __builtin_nontemporal_store(v1, &outT[(size_t)(B0 + q * 4 + 1) * DIM + cb + n]);
                __builtin_nontemporal_store(v2, &outT[(size_t)(B0 + q * 4 + 2) * DIM + cb + n]);
                __builtin_nontemporal_store(v3, &outT[(size_t)(B0 + q * 4 + 3) * DIM + cb + n]);
            }

            if (t < SEQ - 1) {
                if (tid < GRP) {
                    const unsigned* slot = &scanflags[(bt * GRP + tid) * FLAGSTR];
                    while (__hip_atomic_load(slot, __ATOMIC_RELAXED,
                                             __HIP_MEMORY_SCOPE_AGENT) < (unsigned)(t + 1))
                        __builtin_amdgcn_s_sleep(1);
                }
                __syncthreads();
            }
        }
    }
}

// ---------------------------------------------------------------------------
extern "C" void kernel_launch(void* const* d_in, const int* in_sizes, int n_in,
                              void* d_out, int out_size, void* d_ws, size_t ws_size,
                              hipStream_t stream) {
    const float* x  = (const float*)d_in[0];   // [S,B,D]
    const float* h0 = (const float*)d_in[1];   // [B,D]
    const float* Wx = (const float*)d_in[2];   // [D,D]
    const float* Wh = (const float*)d_in[3];   // [D,D]
    const float* b  = (const float*)d_in[4];   // [D]
    float* out = (float*)d_out;                // [S,B,D]
    unsigned* scanflags = (unsigned*)d_ws;                          // 8 KB
    unsigned* xpflags   = (unsigned*)((char*)d_ws + 8192);          // 16 KB
    unsigned short* hX  = (unsigned short*)((char*)d_ws + 24576);   // 512 KB

    hipMemsetAsync(d_ws, 0, 24576, stream);

    rnn_fused<<<dim3(TNB), dim3(512), 0, stream>>>(
        x, h0, Wx, Wh, b, out, scanflags, xpflags, hX);
}

// Round 5
// 1010.556 us; speedup vs baseline: 1.5589x; 1.5589x over previous
//
#include <hip/hip_runtime.h>
#include <math.h>

// RNNLayer: out[t] = tanh(x[t] @ Wx + b + h_{t-1} @ Wh), h_{-1} = h0
// S=128, B=128, D=1024. Inputs/outputs fp32.
//
// Round 10: revert to round-3 two-kernel structure (800 us verified); round-4
// fusion regressed 2x from VGPR spill (launch_bounds cap + two-role regalloc
// -> 64 VGPR + 1.7 GB scratch traffic). Changes vs round 3:
//
// Phase 0 (new): xcv pre-converts x ONCE to bf16 hi+lo in workspace, laid out
//   as xp's exact LDS tile image (row stride 2048 B, 16-B blocks XOR-swizzled
//   by (row&7)<<4 for bank spread; swizzle baked into the GLOBAL layout).
//   ~128 MB traffic ~= 30 us.
// Phase 1: xp_fast stages tiles as a pure linear copy (8 x 16B loads ->
//   8 x ds_write_b128 per thread, ZERO convert VALU), prefetched one step
//   ahead into registers (T14). MFMA identical to round 3 (hh+lh+hl, bf16
//   hi/lo Wx resident, k-half waves) -> bit-identical numerics.
//   XCD-affine block decode: the 16 col-blocks sharing a (tg,bt) x-slab sit
//   on one XCD -> slab read 16x from that XCD's L2, not 16x from L3.
//   Fallback: if ws_size < 65 MB, runs round-3's xp_pers (convert in-kernel).
// Phase 2: rnn_scan = round-3 scan verbatim except: XCD-affine decode
//   (bt = blockIdx&7: barrier groups intra-XCD), out[] nt-stores moved after
//   the flag post (vmcnt(0) drain waits only the single hX store), s_sleep(1).
//
// Workspace: scanflags 8 KB @0, hX 512 KB @8192, xw 64 MB @1 MB.

#define DIM 1024
#define BATCH 128
#define SEQ 128
#define BD (BATCH * DIM)
#define NBLK 128
#define GRP 16        // scan blocks per batch-group
#define HSTR 1032     // scan LDS row stride in ushorts (bank spread)
#define FLAGSTR 16    // uints per flag slot (64 B)
#define XNB 256       // xp blocks
#define HXGRP 16384   // ushorts per hX group slab (16 rows x 1024 cols)
#define XW_OFF (1u << 20)
#define XW_BYTES (64u << 20)

typedef __attribute__((ext_vector_type(8))) short bf16x8;
typedef __attribute__((ext_vector_type(4))) float f32x4;

static __device__ __forceinline__ unsigned short f2bf_rne(float f) {
    unsigned u = __builtin_bit_cast(unsigned, f);
    unsigned r = (u + 0x7FFFu + ((u >> 16) & 1u)) >> 16;
    return (unsigned short)r;
}
static __device__ __forceinline__ float bf2f(unsigned short h) {
    return __builtin_bit_cast(float, ((unsigned)h) << 16);
}

// ---------------------------------------------------------------------------
// Phase 0: x -> bf16 hi/lo, pre-swizzled LDS-image layout.
// Slab (t,bt): 64 KB = [hi 16x2048B][lo 16x2048B]; element (row,col) at
// byte row*2048 + (((col/8)*16) ^ ((row&7)<<4)) + (col%8)*2 (+32768 for lo).
// ---------------------------------------------------------------------------
__global__ __launch_bounds__(256) void xcv(
    const float* __restrict__ x, unsigned short* __restrict__ xw)
{
    const int blk = blockIdx.x;          // 1024 = 128 t x 8 bt
    const int t  = blk >> 3;
    const int bt = blk & 7;
    const float* src = x + (size_t)t * BD + (size_t)bt * 16 * DIM;
    char* slab = (char*)xw + (size_t)blk * 65536;
    const int tid = threadIdx.x;

    #pragma unroll
    for (int uu = 0; uu < 8; ++uu) {
        const int u = tid + uu * 256;    // 2048 units = 16 rows x 128 col-blocks
        const int row = u >> 7;
        const int cb8 = u & 127;
        const float4 a = *(const float4*)&src[(size_t)row * DIM + cb8 * 8];
        const float4 c = *(const float4*)&src[(size_t)row * DIM + cb8 * 8 + 4];
        const float f[8] = {a.x, a.y, a.z, a.w, c.x, c.y, c.z, c.w};
        unsigned hh[8], ll[8];
        #pragma unroll
        for (int j = 0; j < 8; ++j) {
            const unsigned short h = f2bf_rne(f[j]);
            hh[j] = h;
            ll[j] = f2bf_rne(f[j] - bf2f(h));
        }
        uint4 hv, lv;
        hv.x = hh[0] | (hh[1] << 16);  hv.y = hh[2] | (hh[3] << 16);
        hv.z = hh[4] | (hh[5] << 16);  hv.w = hh[6] | (hh[7] << 16);
        lv.x = ll[0] | (ll[1] << 16);  lv.y = ll[2] | (ll[3] << 16);
        lv.z = ll[4] | (ll[5] << 16);  lv.w = ll[6] | (ll[7] << 16);
        const size_t off = (size_t)row * 2048
                         + (size_t)(((unsigned)(cb8 << 4)) ^ (unsigned)((row & 7) << 4));
        *(uint4*)(slab + off) = hv;
        *(uint4*)(slab + off + 32768) = lv;
    }
}

// ---------------------------------------------------------------------------
// Phase 1 (fast): persistent xp GEMM on pre-converted x.
// XCD-affine decode: g = bid&7 selects the XCD-group; the 16 ct-blocks of a
// (tg,bt) have ids congruent mod 8 -> same XCD (round-robin dispatch).
// Wave w: col-tile (w>>1), k-half (w&1). Wx bf16 hi/lo resident (128 VGPRs).
// ---------------------------------------------------------------------------
__global__ __launch_bounds__(512) void xp_fast(
    const unsigned short* __restrict__ xw,
    const float* __restrict__ Wx,
    const float* __restrict__ bias,
    float* __restrict__ out)
{
    __shared__ char xbuf[65536];    // 64 KB: [hi 16x2048][lo 16x2048], swizzled image
    __shared__ f32x4 redS[256];     // 4 KB

    const int tid = threadIdx.x;
    const int p = blockIdx.x;
    const int g = p & 7;
    const int slot = p >> 3;
    const int idx = g + 8 * (slot >> 4);   // 0..15 = (tg,bt)
    const int ct = slot & 15;
    const int tg = idx >> 3;
    const int bt = idx & 7;
    const int B0 = bt * 16;
    const int Cb = ct * 64;

    const int w = tid >> 6;
    const int l = tid & 63;
    const int n = l & 15;
    const int q = l >> 4;
    const int cb = Cb + (w >> 1) * 16;
    const int K0 = (w & 1) * 512;

    // resident Wx fragments (bf16 hi + lo), k-half split
    bf16x8 Bhi[16], Blo[16];
    #pragma unroll
    for (int s = 0; s < 16; ++s) {
        bf16x8 hi, lo;
        #pragma unroll
        for (int j = 0; j < 8; ++j) {
            const int k = K0 + 32 * s + q * 8 + j;
            const float wv = Wx[(size_t)k * DIM + cb + n];
            const unsigned short h16 = f2bf_rne(wv);
            hi[j] = (short)h16;
            lo[j] = (short)f2bf_rne(wv - bf2f(h16));
        }
        Bhi[s] = hi;
        Blo[s] = lo;
    }
    const float bv = bias[cb + n];

    const int t0 = tg * 64;
    const unsigned swzr = (unsigned)((l & 7) << 4);       // row = l&15
    const char* hb = xbuf + (size_t)(l & 15) * 2048;

    // prologue: stage tile t0 (linear copy: regs -> LDS)
    uint4 xr[8];
    {
        const char* slab = (const char*)xw + (size_t)(t0 * 8 + bt) * 65536;
        #pragma unroll
        for (int r = 0; r < 8; ++r)
            xr[r] = *(const uint4*)(slab + tid * 16 + r * 8192);
        #pragma unroll
        for (int r = 0; r < 8; ++r)
            *(uint4*)(xbuf + tid * 16 + r * 8192) = xr[r];
    }

    for (int tt = 0; tt < 64; ++tt) {
        __syncthreads();   // B1: xbuf tile tt ready; redS consumed

        // prefetch next tile into registers (latency hides under MFMA)
        if (tt + 1 < 64) {
            const char* slab = (const char*)xw + (size_t)((t0 + tt + 1) * 8 + bt) * 65536;
            #pragma unroll
            for (int r = 0; r < 8; ++r)
                xr[r] = *(const uint4*)(slab + tid * 16 + r * 8192);
        }

        // MFMA over this wave's k-half: hh + lh + hl (identical to round 3)
        f32x4 acc = {0.f, 0.f, 0.f, 0.f};
        #pragma unroll
        for (int s = 0; s < 16; ++s) {
            const int off = (int)(((unsigned)(K0 * 2 + 64 * s + 16 * q)) ^ swzr);
            const bf16x8 ah = *(const bf16x8*)(hb + off);
            const bf16x8 al = *(const bf16x8*)(hb + off + 32768);
            acc = __builtin_amdgcn_mfma_f32_16x16x32_bf16(ah, Bhi[s], acc, 0, 0, 0);
            acc = __builtin_amdgcn_mfma_f32_16x16x32_bf16(al, Bhi[s], acc, 0, 0, 0);
            acc = __builtin_amdgcn_mfma_f32_16x16x32_bf16(ah, Blo[s], acc, 0, 0, 0);
        }

        if (w & 1) redS[(w >> 1) * 64 + l] = acc;
        __syncthreads();   // B2: drains all LDS reads of xbuf

        if (!(w & 1)) {
            const f32x4 pr = redS[(w >> 1) * 64 + l];
            float* outT = out + (size_t)(t0 + tt) * BD;
            #pragma unroll
            for (int i = 0; i < 4; ++i)
                outT[(size_t)(B0 + q * 4 + i) * DIM + cb + n] = acc[i] + pr[i] + bv;
        }

        // write prefetched tile into (now free) xbuf
        if (tt + 1 < 64) {
            #pragma unroll
            for (int r = 0; r < 8; ++r)
                *(uint4*)(xbuf + tid * 16 + r * 8192) = xr[r];
        }
    }
}

// ---------------------------------------------------------------------------
// Phase 1 (fallback, ws too small): round-3 xp_pers verbatim.
// ---------------------------------------------------------------------------
__global__ __launch_bounds__(512) void xp_pers(
    const float* __restrict__ x,
    const float* __restrict__ Wx,
    const float* __restrict__ bias,
    float* __restrict__ out)
{
    __shared__ unsigned short hHi[16 * HSTR];
    __shared__ unsigned short hLo[16 * HSTR];
    __shared__ f32x4 redS[256];

    const int tid = threadIdx.x;
    const int bid = blockIdx.x;
    const int tg  = bid >> 7;
    const int bt  = (bid >> 4) & 7;
    const int ct  = bid & 15;
    const int B0  = bt * 16;
    const int Cb  = ct * 64;
    const int NT  = SEQ / 2;

    const int w = tid >> 6;
    const int l = tid & 63;
    const int n = l & 15;
    const int q = l >> 4;
    const int cb = Cb + (w >> 1) * 16;
    const int K0 = (w & 1) * 512;

    bf16x8 Bhi[16], Blo[16];
    #pragma unroll
    for (int s = 0; s < 16; ++s) {
        bf16x8 hi, lo;
        #pragma unroll
        for (int j = 0; j < 8; ++j) {
            const int k = K0 + 32 * s + q * 8 + j;
            const float wv = Wx[(size_t)k * DIM + cb + n];
            const unsigned short h16 = f2bf_rne(wv);
            hi[j] = (short)h16;
            lo[j] = (short)f2bf_rne(wv - bf2f(h16));
        }
        Bhi[s] = hi;
        Blo[s] = lo;
    }
    const float bv = bias[cb + n];

    const int sr = tid >> 5;
    const int su = tid & 31;

    {
        const float* xT = x + (size_t)(tg * NT) * BD + (size_t)B0 * DIM;
        const unsigned long long* srow = (const unsigned long long*)(xT + (size_t)sr * DIM);
        unsigned short* dh = &hHi[sr * HSTR];
        unsigned short* dl = &hLo[sr * HSTR];
        #pragma unroll
        for (int i = 0; i < 16; ++i) {
            const unsigned long long v = srow[su + 32 * i];
            const float f0 = __builtin_bit_cast(float, (unsigned)(v & 0xFFFFFFFFull));
            const float f1 = __builtin_bit_cast(float, (unsigned)(v >> 32));
            const unsigned short h0 = f2bf_rne(f0);
            const unsigned short h1 = f2bf_rne(f1);
            const unsigned short l0 = f2bf_rne(f0 - bf2f(h0));
            const unsigned short l1 = f2bf_rne(f1 - bf2f(h1));
            *(unsigned*)(dh + 2 * (su + 32 * i)) = (unsigned)h0 | ((unsigned)h1 << 16);
            *(unsigned*)(dl + 2 * (su + 32 * i)) = (unsigned)l0 | ((unsigned)l1 << 16);
        }
    }

    for (int tt = 0; tt < NT; ++tt) {
        const int t = tg * NT + tt;
        float* outT = out + (size_t)t * BD;

        __syncthreads();

        unsigned long long xr[16];
        if (tt + 1 < NT) {
            const float* xN = x + (size_t)(t + 1) * BD + (size_t)B0 * DIM;
            const unsigned long long* srow = (const unsigned long long*)(xN + (size_t)sr * DIM);
            #pragma unroll
            for (int i = 0; i < 16; ++i) xr[i] = srow[su + 32 * i];
        }

        f32x4 acc = {0.f, 0.f, 0.f, 0.f};
        {
            const unsigned short* rh = &hHi[(l & 15) * HSTR + K0];
            const unsigned short* rl = &hLo[(l & 15) * HSTR + K0];
            #pragma unroll
            for (int s = 0; s < 16; ++s) {
                const bf16x8 ah = *(const bf16x8*)(rh + 32 * s + 8 * q);
                const bf16x8 al = *(const bf16x8*)(rl + 32 * s + 8 * q);
                acc = __builtin_amdgcn_mfma_f32_16x16x32_bf16(ah, Bhi[s], acc, 0, 0, 0);
                acc = __builtin_amdgcn_mfma_f32_16x16x32_bf16(al, Bhi[s], acc, 0, 0, 0);
                acc = __builtin_amdgcn_mfma_f32_16x16x32_bf16(ah, Blo[s], acc, 0, 0, 0);
            }
        }

        if (w & 1) redS[(w >> 1) * 64 + l] = acc;
        __syncthreads();

        if (!(w & 1)) {
            const f32x4 p = redS[(w >> 1) * 64 + l];
            #pragma unroll
            for (int i = 0; i < 4; ++i)
                outT[(size_t)(B0 + q * 4 + i) * DIM + cb + n] = acc[i] + p[i] + bv;
        }

        if (tt + 1 < NT) {
            unsigned short* dh = &hHi[sr * HSTR];
            unsigned short* dl = &hLo[sr * HSTR];
            #pragma unroll
            for (int i = 0; i < 16; ++i) {
                const unsigned long long v = xr[i];
                const float f0 = __builtin_bit_cast(float, (unsigned)(v & 0xFFFFFFFFull));
                const float f1 = __builtin_bit_cast(float, (unsigned)(v >> 32));
                const unsigned short h0 = f2bf_rne(f0);
                const unsigned short h1 = f2bf_rne(f1);
                const unsigned short l0 = f2bf_rne(f0 - bf2f(h0));
                const unsigned short l1 = f2bf_rne(f1 - bf2f(h1));
                *(unsigned*)(dh + 2 * (su + 32 * i)) = (unsigned)h0 | ((unsigned)h1 << 16);
                *(unsigned*)(dl + 2 * (su + 32 * i)) = (unsigned)l0 | ((unsigned)l1 << 16);
            }
        }
    }
}

// ---------------------------------------------------------------------------
// Phase 2: persistent MFMA scan (round-3 verbatim + XCD-affine decode,
// out-stores after flag post, s_sleep(1)).
// ---------------------------------------------------------------------------
__global__ __launch_bounds__(512) void rnn_scan(
    const float* __restrict__ h0,
    const float* __restrict__ Wh,
    float* out,
    unsigned* flags,
    unsigned short* hX)
{
    __shared__ unsigned short hS[16 * HSTR];
    __shared__ f32x4 redS[256];

    const int tid = threadIdx.x;
    const int p   = blockIdx.x;
    const int bt  = p & 7;           // XCD-affine: all 16 blocks of bt share XCD
    const int ct  = p >> 3;
    const int lbid = bt * 16 + ct;   // logical id for flag slots
    const int B0  = bt * 16;
    const int Cb  = ct * 64;

    const int w = tid >> 6;
    const int l = tid & 63;
    const int n = l & 15;
    const int q = l >> 4;
    const int cb = Cb + (w >> 1) * 16;
    const int K0 = (w & 1) * 512;

    bf16x8 Bhi[16], Blo[16];
    #pragma unroll
    for (int s = 0; s < 16; ++s) {
        bf16x8 hi, lo;
        #pragma unroll
        for (int j = 0; j < 8; ++j) {
            const int k = K0 + 32 * s + q * 8 + j;
            const float wv = Wh[(size_t)k * DIM + cb + n];
            const unsigned short h16 = f2bf_rne(wv);
            hi[j] = (short)h16;
            lo[j] = (short)f2bf_rne(wv - bf2f(h16));
        }
        Bhi[s] = hi;
        Blo[s] = lo;
    }

    const int sr = tid >> 5;
    const int su = tid & 31;
    const int qq = tid & 3;
    const int c0 = (tid >> 2) & 127;

    for (int t = 0; t < SEQ; ++t) {
        float* outT = out + (size_t)t * BD;

        // xp prefetch (xp_fast/xp_pers completed before this kernel launched)
        float xpv[4];
        if (!(w & 1)) {
            #pragma unroll
            for (int i = 0; i < 4; ++i)
                xpv[i] = __builtin_nontemporal_load(
                    &outT[(size_t)(B0 + q * 4 + i) * DIM + cb + n]);
        }

        if (t == 0) {
            const float* hsrc = h0 + (size_t)B0 * DIM;
            const unsigned long long* srow =
                (const unsigned long long*)(hsrc + (size_t)sr * DIM);
            unsigned short* drow = &hS[sr * HSTR];
            #pragma unroll
            for (int i = 0; i < 16; ++i) {
                const unsigned long long v = srow[su + 32 * i];
                const float f0 = __builtin_bit_cast(float, (unsigned)(v & 0xFFFFFFFFull));
                const float f1 = __builtin_bit_cast(float, (unsigned)(v >> 32));
                const unsigned pk =
                    (unsigned)f2bf_rne(f0) | ((unsigned)f2bf_rne(f1) << 16);
                *(unsigned*)(drow + 2 * (su + 32 * i)) = pk;
            }
        } else {
            const unsigned short* gX = hX + (size_t)((t - 1) & 1) * (8 * HXGRP)
                                          + (size_t)bt * HXGRP;
            #pragma unroll
            for (int half = 0; half < 2; ++half) {
                const int cp = c0 + half * 128;
                unsigned long long L[4];
                #pragma unroll
                for (int cc = 0; cc < 4; ++cc)
                    L[cc] = __hip_atomic_load(
                        (const unsigned long long*)(gX + (size_t)(4 * cp + cc) * 16 + qq * 4),
                        __ATOMIC_RELAXED, __HIP_MEMORY_SCOPE_AGENT);
                #pragma unroll
                for (int i = 0; i < 2; ++i) {
                    const unsigned a0 = (unsigned)(L[0] >> (32 * i));
                    const unsigned a1 = (unsigned)(L[1] >> (32 * i));
                    const unsigned a2 = (unsigned)(L[2] >> (32 * i));
                    const unsigned a3 = (unsigned)(L[3] >> (32 * i));
                    const unsigned r0w0 = (a0 & 0xFFFFu) | (a1 << 16);
                    const unsigned r0w1 = (a2 & 0xFFFFu) | (a3 << 16);
                    const unsigned r1w0 = (a0 >> 16) | (a1 & 0xFFFF0000u);
                    const unsigned r1w1 = (a2 >> 16) | (a3 & 0xFFFF0000u);
                    *(unsigned long long*)&hS[(4 * qq + 2 * i) * HSTR + 4 * cp] =
                        (unsigned long long)r0w0 | ((unsigned long long)r0w1 << 32);
                    *(unsigned long long*)&hS[(4 * qq + 2 * i + 1) * HSTR + 4 * cp] =
                        (unsigned long long)r1w0 | ((unsigned long long)r1w1 << 32);
                }
            }
        }

        __syncthreads();

        f32x4 acc = {0.f, 0.f, 0.f, 0.f};
        {
            const unsigned short* hrow = &hS[(l & 15) * HSTR + K0];
            #pragma unroll
            for (int s = 0; s < 16; ++s) {
                const bf16x8 a = *(const bf16x8*)(hrow + 32 * s + 8 * q);
                acc = __builtin_amdgcn_mfma_f32_16x16x32_bf16(a, Bhi[s], acc, 0, 0, 0);
                acc = __builtin_amdgcn_mfma_f32_16x16x32_bf16(a, Blo[s], acc, 0, 0, 0);
            }
        }

        if (w & 1) redS[(w >> 1) * 64 + l] = acc;
        __syncthreads();

        float v0, v1, v2, v3;
        if (!(w & 1)) {
            const f32x4 pp = redS[(w >> 1) * 64 + l];
            v0 = tanhf(acc[0] + pp[0] + xpv[0]);
            v1 = tanhf(acc[1] + pp[1] + xpv[1]);
            v2 = tanhf(acc[2] + pp[2] + xpv[2]);
            v3 = tanhf(acc[3] + pp[3] + xpv[3]);
            // bf16 side-channel store (the only store gating the flag)
            const unsigned p0 = (unsigned)f2bf_rne(v0) | ((unsigned)f2bf_rne(v1) << 16);
            const unsigned p1 = (unsigned)f2bf_rne(v2) | ((unsigned)f2bf_rne(v3) << 16);
            unsigned short* gW = hX + (size_t)(t & 1) * (8 * HXGRP) + (size_t)bt * HXGRP;
            __hip_atomic_store(
                (unsigned long long*)(gW + (size_t)(cb + n) * 16 + q * 4),
                (unsigned long long)p0 | ((unsigned long long)p1 << 32),
                __ATOMIC_RELAXED, __HIP_MEMORY_SCOPE_AGENT);
        }

        if (t < SEQ - 1) {
            // drain hX store to the coherence point, then post my flag
            asm volatile("s_waitcnt vmcnt(0)" ::: "memory");
            __syncthreads();
            if (tid == 0)
                __hip_atomic_store(&flags[lbid * FLAGSTR], (unsigned)(t + 1),
                                   __ATOMIC_RELAXED, __HIP_MEMORY_SCOPE_AGENT);
        }

        // fp32 output stores AFTER the flag: they complete under the spin
        if (!(w & 1)) {
            __builtin_nontemporal_store(v0, &outT[(size_t)(B0 + q * 4 + 0) * DIM + cb + n]);
            __builtin_nontemporal_store(v1, &outT[(size_t)(B0 + q * 4 + 1) * DIM + cb + n]);
            __builtin_nontemporal_store(v2, &outT[(size_t)(B0 + q * 4 + 2) * DIM + cb + n]);
            __builtin_nontemporal_store(v3, &outT[(size_t)(B0 + q * 4 + 3) * DIM + cb + n]);
        }

        if (t < SEQ - 1) {
            if (tid < GRP) {
                const unsigned* slot = &flags[(bt * GRP + tid) * FLAGSTR];
                while (__hip_atomic_load(slot, __ATOMIC_RELAXED,
                                         __HIP_MEMORY_SCOPE_AGENT) < (unsigned)(t + 1))
                    __builtin_amdgcn_s_sleep(1);
            }
            __syncthreads();
        }
    }
}

// ---------------------------------------------------------------------------
extern "C" void kernel_launch(void* const* d_in, const int* in_sizes, int n_in,
                              void* d_out, int out_size, void* d_ws, size_t ws_size,
                              hipStream_t stream) {
    const float* x  = (const float*)d_in[0];   // [S,B,D]
    const float* h0 = (const float*)d_in[1];   // [B,D]
    const float* Wx = (const float*)d_in[2];   // [D,D]
    const float* Wh = (const float*)d_in[3];   // [D,D]
    const float* b  = (const float*)d_in[4];   // [D]
    float* out = (float*)d_out;                // [S,B,D]
    unsigned* flags = (unsigned*)d_ws;                            // 8 KB
    unsigned short* hX = (unsigned short*)((char*)d_ws + 8192);   // 512 KB
    unsigned short* xw = (unsigned short*)((char*)d_ws + XW_OFF); // 64 MB

    hipMemsetAsync(d_ws, 0, NBLK * FLAGSTR * sizeof(unsigned), stream);

    if (ws_size >= (size_t)XW_OFF + (size_t)XW_BYTES) {
        xcv<<<dim3(1024), dim3(256), 0, stream>>>(x, xw);
        xp_fast<<<dim3(XNB), dim3(512), 0, stream>>>(xw, Wx, b, out);
    } else {
        xp_pers<<<dim3(XNB), dim3(512), 0, stream>>>(x, Wx, b, out);
    }

    rnn_scan<<<dim3(NBLK), dim3(512), 0, stream>>>(h0, Wh, out, flags, hX);
}

// Round 6
// 870.962 us; speedup vs baseline: 1.8088x; 1.1603x over previous
//
#include <hip/hip_runtime.h>
#include <math.h>

// RNNLayer: out[t] = tanh(x[t] @ Wx + b + h_{t-1} @ Wh), h_{-1} = h0
// S=128, B=128, D=1024. Inputs/outputs fp32.
//
// Round 11: revert phase 1 to the VERIFIED round-3 xp_pers (round-5's
// xcv+xp_fast was 533 us vs 277, and its counters were invisible -> revert,
// don't debug blind). Changes on top of verified parts:
//
// Phase 1 xp_pers (verified 277 us) + three mechanism-clear tweaks:
//   - next-tile prefetch issued BEFORE the tile barrier (loads touch no LDS,
//     so they gain barrier+MFMA of latency cover);
//   - hi/lo split via bit-truncation: hi = top16(f) (2 bit-ops), lo =
//     rne(f - trunc(f)); hi+lo == f to ~2^-17, absmax unchanged;
//   - XCD-affine decode: the 16 ct-blocks sharing an x-slab (tg,bt) are
//     congruent mod 16 -> same XCD under round-robin dispatch (perf-only).
// Phase 2 rnn_scan (verified 477 us) + per-wave counter flag-post:
//   - OLD: vmcnt(0) all waves -> __syncthreads -> tid0 posts flag (post waits
//     max over 8 waves + a barrier).
//   - NEW: each even wave drains ITS OWN stores (s_waitcnt is wave-scoped)
//     and lane 0 atomic-adds +1 to the block counter; consumers spin for
//     cnt >= 4*(t+1). Safety: the increment follows the redS __syncthreads,
//     which every stager of slab (t-1)&1 has passed -> parity reuse is still
//     race-free. One barrier/step removed, post happens earlier.
// Workspace: flags 8 KB @0, hX 512 KB @8192.

#define DIM 1024
#define BATCH 128
#define SEQ 128
#define BD (BATCH * DIM)
#define NBLK 128
#define GRP 16        // scan blocks per batch-group
#define HSTR 1032     // LDS row stride in ushorts (bank spread)
#define FLAGSTR 16    // uints per flag slot (64 B)
#define XNB 256       // xp blocks
#define HXGRP 16384   // ushorts per hX group slab (16 rows x 1024 cols)

typedef __attribute__((ext_vector_type(8))) short bf16x8;
typedef __attribute__((ext_vector_type(4))) float f32x4;

static __device__ __forceinline__ unsigned short f2bf_rne(float f) {
    unsigned u = __builtin_bit_cast(unsigned, f);
    unsigned r = (u + 0x7FFFu + ((u >> 16) & 1u)) >> 16;
    return (unsigned short)r;
}
static __device__ __forceinline__ float bf2f(unsigned short h) {
    return __builtin_bit_cast(float, ((unsigned)h) << 16);
}

// split a packed fp32 pair into bf16 hi (truncation) + lo (rne of residual):
// hi+lo reproduces f to ~2^-17; cheaper than double-rne (hi is 2 bit-ops,
// residual subtracts (u & 0xFFFF0000) with no rounding step).
static __device__ __forceinline__ void split_pair(
    unsigned long long v, unsigned& hp, unsigned& lp)
{
    const unsigned u0 = (unsigned)v;
    const unsigned u1 = (unsigned)(v >> 32);
    const float f0 = __builtin_bit_cast(float, u0);
    const float f1 = __builtin_bit_cast(float, u1);
    hp = (u0 >> 16) | (u1 & 0xFFFF0000u);
    const float r0 = f0 - __builtin_bit_cast(float, u0 & 0xFFFF0000u);
    const float r1 = f1 - __builtin_bit_cast(float, u1 & 0xFFFF0000u);
    lp = (unsigned)f2bf_rne(r0) | ((unsigned)f2bf_rne(r1) << 16);
}

// ---------------------------------------------------------------------------
// Phase 1: persistent xp GEMM (round-3 structure, verified).
// XCD-affine decode: g = bid&15 selects (tg,bt); blocks sharing an x-slab
// are congruent mod 16 -> same XCD under round-robin (perf heuristic only).
// Wave w: col-tile (w>>1), k-half (w&1). Wx bf16 hi/lo register-resident.
// ---------------------------------------------------------------------------
__global__ __launch_bounds__(512) void xp_pers(
    const float* __restrict__ x,
    const float* __restrict__ Wx,
    const float* __restrict__ bias,
    float* __restrict__ out)
{
    __shared__ unsigned short hHi[16 * HSTR];
    __shared__ unsigned short hLo[16 * HSTR];
    __shared__ f32x4 redS[256];

    const int tid = threadIdx.x;
    const int bid = blockIdx.x;
    const int g   = bid & 15;        // (tg,bt)
    const int ct  = bid >> 4;        // 0..15
    const int tg  = g >> 3;
    const int bt  = g & 7;
    const int B0  = bt * 16;
    const int Cb  = ct * 64;
    const int NT  = SEQ / 2;

    const int w = tid >> 6;
    const int l = tid & 63;
    const int n = l & 15;
    const int q = l >> 4;
    const int cb = Cb + (w >> 1) * 16;
    const int K0 = (w & 1) * 512;

    // resident Wx fragments (bf16 hi + lo), k-half split
    bf16x8 Bhi[16], Blo[16];
    #pragma unroll
    for (int s = 0; s < 16; ++s) {
        bf16x8 hi, lo;
        #pragma unroll
        for (int j = 0; j < 8; ++j) {
            const int k = K0 + 32 * s + q * 8 + j;
            const float wv = Wx[(size_t)k * DIM + cb + n];
            const unsigned short h16 = f2bf_rne(wv);
            hi[j] = (short)h16;
            lo[j] = (short)f2bf_rne(wv - bf2f(h16));
        }
        Bhi[s] = hi;
        Blo[s] = lo;
    }
    const float bv = bias[cb + n];

    const int sr = tid >> 5;    // staging: row 0..15 (32 threads per row)
    const int su = tid & 31;    // staging: ulong lane within row

    // prologue: stage step tg*NT fully
    {
        const float* xT = x + (size_t)(tg * NT) * BD + (size_t)B0 * DIM;
        const unsigned long long* srow =
            (const unsigned long long*)(xT + (size_t)sr * DIM);
        unsigned short* dh = &hHi[sr * HSTR];
        unsigned short* dl = &hLo[sr * HSTR];
        #pragma unroll
        for (int i = 0; i < 16; ++i) {
            unsigned hp, lp;
            split_pair(srow[su + 32 * i], hp, lp);
            *(unsigned*)(dh + 2 * (su + 32 * i)) = hp;
            *(unsigned*)(dl + 2 * (su + 32 * i)) = lp;
        }
    }

    for (int tt = 0; tt < NT; ++tt) {
        const int t = tg * NT + tt;
        float* outT = out + (size_t)t * BD;

        // issue NEXT step's x loads BEFORE the barrier (no LDS dependency:
        // this thread's own convert/write of tile tt finished last iter)
        unsigned long long xr[16];
        if (tt + 1 < NT) {
            const float* xN = x + (size_t)(t + 1) * BD + (size_t)B0 * DIM;
            const unsigned long long* srow =
                (const unsigned long long*)(xN + (size_t)sr * DIM);
            #pragma unroll
            for (int i = 0; i < 16; ++i) xr[i] = srow[su + 32 * i];
        }

        __syncthreads();   // B1: LDS tile tt ready; redS consumed

        // MFMA over this wave's k-half: hh + lh + hl
        f32x4 acc = {0.f, 0.f, 0.f, 0.f};
        {
            const unsigned short* rh = &hHi[(l & 15) * HSTR + K0];
            const unsigned short* rl = &hLo[(l & 15) * HSTR + K0];
            #pragma unroll
            for (int s = 0; s < 16; ++s) {
                const bf16x8 ah = *(const bf16x8*)(rh + 32 * s + 8 * q);
                const bf16x8 al = *(const bf16x8*)(rl + 32 * s + 8 * q);
                acc = __builtin_amdgcn_mfma_f32_16x16x32_bf16(ah, Bhi[s], acc, 0, 0, 0);
                acc = __builtin_amdgcn_mfma_f32_16x16x32_bf16(al, Bhi[s], acc, 0, 0, 0);
                acc = __builtin_amdgcn_mfma_f32_16x16x32_bf16(ah, Blo[s], acc, 0, 0, 0);
            }
        }

        if (w & 1) redS[(w >> 1) * 64 + l] = acc;
        __syncthreads();   // B2: all LDS reads of tile tt done

        if (!(w & 1)) {
            const f32x4 p = redS[(w >> 1) * 64 + l];
            // C/D layout: col = lane&15, row = q*4 + reg
            #pragma unroll
            for (int i = 0; i < 4; ++i)
                outT[(size_t)(B0 + q * 4 + i) * DIM + cb + n] = acc[i] + p[i] + bv;
        }

        // convert + write NEXT step's tile into the (now free) LDS buffer
        if (tt + 1 < NT) {
            unsigned short* dh = &hHi[sr * HSTR];
            unsigned short* dl = &hLo[sr * HSTR];
            #pragma unroll
            for (int i = 0; i < 16; ++i) {
                unsigned hp, lp;
                split_pair(xr[i], hp, lp);
                *(unsigned*)(dh + 2 * (su + 32 * i)) = hp;
                *(unsigned*)(dl + 2 * (su + 32 * i)) = lp;
            }
        }
    }
}

// ---------------------------------------------------------------------------
// Phase 2: persistent MFMA scan (round-5 structure, verified 477 us) with
// per-wave counter flag-post. Block: bt = bid&7 (XCD-affine), ct = bid>>3.
// ---------------------------------------------------------------------------
__global__ __launch_bounds__(512) void rnn_scan(
    const float* __restrict__ h0,
    const float* __restrict__ Wh,
    float* out,
    unsigned* flags,
    unsigned short* hX)
{
    __shared__ unsigned short hS[16 * HSTR];
    __shared__ f32x4 redS[256];

    const int tid = threadIdx.x;
    const int p   = blockIdx.x;
    const int bt  = p & 7;           // XCD-affine: group bt lives on one XCD
    const int ct  = p >> 3;
    const int lbid = bt * 16 + ct;   // logical id for flag slots
    const int B0  = bt * 16;
    const int Cb  = ct * 64;

    const int w = tid >> 6;
    const int l = tid & 63;
    const int n = l & 15;
    const int q = l >> 4;
    const int cb = Cb + (w >> 1) * 16;
    const int K0 = (w & 1) * 512;

    bf16x8 Bhi[16], Blo[16];
    #pragma unroll
    for (int s = 0; s < 16; ++s) {
        bf16x8 hi, lo;
        #pragma unroll
        for (int j = 0; j < 8; ++j) {
            const int k = K0 + 32 * s + q * 8 + j;
            const float wv = Wh[(size_t)k * DIM + cb + n];
            const unsigned short h16 = f2bf_rne(wv);
            hi[j] = (short)h16;
            lo[j] = (short)f2bf_rne(wv - bf2f(h16));
        }
        Bhi[s] = hi;
        Blo[s] = lo;
    }

    const int sr = tid >> 5;
    const int su = tid & 31;
    const int qq = tid & 3;
    const int c0 = (tid >> 2) & 127;

    for (int t = 0; t < SEQ; ++t) {
        float* outT = out + (size_t)t * BD;

        // xp prefetch (xp_pers completed before this kernel launched)
        float xpv[4];
        if (!(w & 1)) {
            #pragma unroll
            for (int i = 0; i < 4; ++i)
                xpv[i] = __builtin_nontemporal_load(
                    &outT[(size_t)(B0 + q * 4 + i) * DIM + cb + n]);
        }

        if (t == 0) {
            const float* hsrc = h0 + (size_t)B0 * DIM;
            const unsigned long long* srow =
                (const unsigned long long*)(hsrc + (size_t)sr * DIM);
            unsigned short* drow = &hS[sr * HSTR];
            #pragma unroll
            for (int i = 0; i < 16; ++i) {
                const unsigned long long v = srow[su + 32 * i];
                const float f0 = __builtin_bit_cast(float, (unsigned)(v & 0xFFFFFFFFull));
                const float f1 = __builtin_bit_cast(float, (unsigned)(v >> 32));
                const unsigned pk =
                    (unsigned)f2bf_rne(f0) | ((unsigned)f2bf_rne(f1) << 16);
                *(unsigned*)(drow + 2 * (su + 32 * i)) = pk;
            }
        } else {
            // bf16 side-channel: 8 x 8B bypass loads + in-register transpose
            const unsigned short* gX = hX + (size_t)((t - 1) & 1) * (8 * HXGRP)
                                          + (size_t)bt * HXGRP;
            #pragma unroll
            for (int half = 0; half < 2; ++half) {
                const int cp = c0 + half * 128;
                unsigned long long L[4];
                #pragma unroll
                for (int cc = 0; cc < 4; ++cc)
                    L[cc] = __hip_atomic_load(
                        (const unsigned long long*)(gX + (size_t)(4 * cp + cc) * 16 + qq * 4),
                        __ATOMIC_RELAXED, __HIP_MEMORY_SCOPE_AGENT);
                #pragma unroll
                for (int i = 0; i < 2; ++i) {
                    const unsigned a0 = (unsigned)(L[0] >> (32 * i));
                    const unsigned a1 = (unsigned)(L[1] >> (32 * i));
                    const unsigned a2 = (unsigned)(L[2] >> (32 * i));
                    const unsigned a3 = (unsigned)(L[3] >> (32 * i));
                    const unsigned r0w0 = (a0 & 0xFFFFu) | (a1 << 16);
                    const unsigned r0w1 = (a2 & 0xFFFFu) | (a3 << 16);
                    const unsigned r1w0 = (a0 >> 16) | (a1 & 0xFFFF0000u);
                    const unsigned r1w1 = (a2 >> 16) | (a3 & 0xFFFF0000u);
                    *(unsigned long long*)&hS[(4 * qq + 2 * i) * HSTR + 4 * cp] =
                        (unsigned long long)r0w0 | ((unsigned long long)r0w1 << 32);
                    *(unsigned long long*)&hS[(4 * qq + 2 * i + 1) * HSTR + 4 * cp] =
                        (unsigned long long)r1w0 | ((unsigned long long)r1w1 << 32);
                }
            }
        }

        __syncthreads();

        f32x4 acc = {0.f, 0.f, 0.f, 0.f};
        {
            const unsigned short* hrow = &hS[(l & 15) * HSTR + K0];
            #pragma unroll
            for (int s = 0; s < 16; ++s) {
                const bf16x8 a = *(const bf16x8*)(hrow + 32 * s + 8 * q);
                acc = __builtin_amdgcn_mfma_f32_16x16x32_bf16(a, Bhi[s], acc, 0, 0, 0);
                acc = __builtin_amdgcn_mfma_f32_16x16x32_bf16(a, Blo[s], acc, 0, 0, 0);
            }
        }

        if (w & 1) redS[(w >> 1) * 64 + l] = acc;
        __syncthreads();   // all waves past this point have finished staging

        if (!(w & 1)) {
            const f32x4 pp = redS[(w >> 1) * 64 + l];
            const float v0 = tanhf(acc[0] + pp[0] + xpv[0]);
            const float v1 = tanhf(acc[1] + pp[1] + xpv[1]);
            const float v2 = tanhf(acc[2] + pp[2] + xpv[2]);
            const float v3 = tanhf(acc[3] + pp[3] + xpv[3]);

            // bf16 side-channel store (the only store gating the counter)
            const unsigned p0 = (unsigned)f2bf_rne(v0) | ((unsigned)f2bf_rne(v1) << 16);
            const unsigned p1 = (unsigned)f2bf_rne(v2) | ((unsigned)f2bf_rne(v3) << 16);
            unsigned short* gW = hX + (size_t)(t & 1) * (8 * HXGRP) + (size_t)bt * HXGRP;
            __hip_atomic_store(
                (unsigned long long*)(gW + (size_t)(cb + n) * 16 + q * 4),
                (unsigned long long)p0 | ((unsigned long long)p1 << 32),
                __ATOMIC_RELAXED, __HIP_MEMORY_SCOPE_AGENT);

            if (t < SEQ - 1) {
                // drain THIS WAVE's stores (s_waitcnt is wave-scoped), then
                // bump the block counter: 4 even waves x +1 = +4 per step.
                asm volatile("s_waitcnt vmcnt(0)" ::: "memory");
                if (l == 0)
                    __hip_atomic_fetch_add(&flags[lbid * FLAGSTR], 1u,
                                           __ATOMIC_RELAXED, __HIP_MEMORY_SCOPE_AGENT);
            }

            // fp32 output stores AFTER the post: complete under the spin
            __builtin_nontemporal_store(v0, &outT[(size_t)(B0 + q * 4 + 0) * DIM + cb + n]);
            __builtin_nontemporal_store(v1, &outT[(size_t)(B0 + q * 4 + 1) * DIM + cb + n]);
            __builtin_nontemporal_store(v2, &outT[(size_t)(B0 + q * 4 + 2) * DIM + cb + n]);
            __builtin_nontemporal_store(v3, &outT[(size_t)(B0 + q * 4 + 3) * DIM + cb + n]);
        }

        if (t < SEQ - 1) {
            // threads 0..15 each watch one block of this bt-group
            if (tid < GRP) {
                const unsigned need = 4u * (unsigned)(t + 1);
                const unsigned* slot = &flags[(bt * GRP + tid) * FLAGSTR];
                while (__hip_atomic_load(slot, __ATOMIC_RELAXED,
                                         __HIP_MEMORY_SCOPE_AGENT) < need)
                    __builtin_amdgcn_s_sleep(1);
            }
            __syncthreads();
        }
    }
}

// ---------------------------------------------------------------------------
extern "C" void kernel_launch(void* const* d_in, const int* in_sizes, int n_in,
                              void* d_out, int out_size, void* d_ws, size_t ws_size,
                              hipStream_t stream) {
    const float* x  = (const float*)d_in[0];   // [S,B,D]
    const float* h0 = (const float*)d_in[1];   // [B,D]
    const float* Wx = (const float*)d_in[2];   // [D,D]
    const float* Wh = (const float*)d_in[3];   // [D,D]
    const float* b  = (const float*)d_in[4];   // [D]
    float* out = (float*)d_out;                // [S,B,D]
    unsigned* flags = (unsigned*)d_ws;                            // 8 KB
    unsigned short* hX = (unsigned short*)((char*)d_ws + 8192);   // 512 KB

    hipMemsetAsync(d_ws, 0, NBLK * FLAGSTR * sizeof(unsigned), stream);

    xp_pers<<<dim3(XNB), dim3(512), 0, stream>>>(x, Wx, b, out);

    rnn_scan<<<dim3(NBLK), dim3(512), 0, stream>>>(h0, Wh, out, flags, hX);
}